// Round 1
// baseline (977.710 us; speedup 1.0000x reference)
//
#include <hip/hip_runtime.h>
#include <hip/hip_bf16.h>
#include <math.h>

// MoE FFN: N=8192 tokens, C=1024, H=4096, E=8, TOP_K=2.
// Round 0: correctness-first bf16 MFMA implementation.
//   router (fp32) -> per-expert compacted token lists
//   fc1: h = gelu(x_gathered @ w1^T)   [bf16 MFMA, fp32 acc]
//   fc2: out += gate * (h @ w2^T)      [atomicAdd fp32 scatter]
// Weights are fp32 in HBM; converted fp32->bf16 during LDS staging (on the fly).
// x pre-converted to bf16 in ws so the A side can use global_load_lds width=16.

#define N_TOK   8192
#define C_DIM   1024
#define H_DIM   4096
#define N_EXP   8
#define CAP     8192   // per-expert worst-case capacity

typedef __bf16 bf16;
typedef bf16  bf16x8 __attribute__((ext_vector_type(8)));
typedef float f32x4  __attribute__((ext_vector_type(4)));

__device__ __forceinline__ void async_ld16(const void* g, void* l) {
    __builtin_amdgcn_global_load_lds(
        (const __attribute__((address_space(1))) void*)g,
        (__attribute__((address_space(3))) void*)l,
        16, 0, 0);
}

__device__ __forceinline__ float gelu_f(float v) {
    float u = v + 0.044715f * v * v * v;
    return 0.5f * v * (1.0f + tanhf(0.7978845608028654f * u));
}

// ---------------- x fp32 -> bf16 ----------------
__global__ void cvt_x_k(const float* __restrict__ x, bf16* __restrict__ xb, int n8) {
    int i = blockIdx.x * blockDim.x + threadIdx.x;
    if (i >= n8) return;
    const float4* p = (const float4*)x + (size_t)i * 2;
    float4 a = p[0], b = p[1];
    bf16x8 v;
    v[0] = (bf16)a.x; v[1] = (bf16)a.y; v[2] = (bf16)a.z; v[3] = (bf16)a.w;
    v[4] = (bf16)b.x; v[5] = (bf16)b.y; v[6] = (bf16)b.z; v[7] = (bf16)b.w;
    *((bf16x8*)xb + i) = v;
}

// ---------------- router: logits -> softmax -> top2 -> compacted lists ----------------
__global__ __launch_bounds__(1024) void router_k(const float* __restrict__ x,
                                                 const float* __restrict__ rw,
                                                 int* __restrict__ counts,
                                                 int* __restrict__ tok,
                                                 float* __restrict__ gate) {
    __shared__ int lcnt[N_EXP];
    __shared__ int lbase[N_EXP];
    const int tid  = threadIdx.x;
    const int lane = tid & 63;
    const int wv   = tid >> 6;          // 16 waves -> 16 tokens per block
    if (tid < N_EXP) lcnt[tid] = 0;
    __syncthreads();

    const int t = blockIdx.x * 16 + wv;

    float dot[N_EXP];
#pragma unroll
    for (int e = 0; e < N_EXP; ++e) dot[e] = 0.f;
    const float4* xr = (const float4*)(x + (size_t)t * C_DIM);
#pragma unroll
    for (int j = 0; j < 4; ++j) {
        float4 xv = xr[j * 64 + lane];
#pragma unroll
        for (int e = 0; e < N_EXP; ++e) {
            float4 w4 = ((const float4*)(rw + (size_t)e * C_DIM))[j * 64 + lane];
            dot[e] += xv.x * w4.x + xv.y * w4.y + xv.z * w4.z + xv.w * w4.w;
        }
    }
#pragma unroll
    for (int e = 0; e < N_EXP; ++e) {
#pragma unroll
        for (int o = 32; o > 0; o >>= 1) dot[e] += __shfl_xor(dot[e], o, 64);
    }

    int a = 0, b = 0, ra = 0, rb = 0;
    float g0 = 0.f, g1 = 0.f;
    if (lane == 0) {
        float m = dot[0];
#pragma unroll
        for (int e = 1; e < N_EXP; ++e) m = fmaxf(m, dot[e]);
        float p[N_EXP]; float s = 0.f;
#pragma unroll
        for (int e = 0; e < N_EXP; ++e) { p[e] = expf(dot[e] - m); s += p[e]; }
        // top-2 (strict > keeps lowest index on ties, matching lax.top_k)
        a = 0;
#pragma unroll
        for (int e = 1; e < N_EXP; ++e) if (p[e] > p[a]) a = e;
        b = -1;
#pragma unroll
        for (int e = 0; e < N_EXP; ++e) if (e != a && (b < 0 || p[e] > p[b])) b = e;
        float pa = p[a] / s, pb = p[b] / s;
        float d = pa + pb + 1e-8f;
        g0 = pa / d; g1 = pb / d;
        ra = atomicAdd(&lcnt[a], 1);
        rb = atomicAdd(&lcnt[b], 1);
    }
    __syncthreads();
    if (tid < N_EXP) lbase[tid] = atomicAdd(&counts[tid], lcnt[tid]);
    __syncthreads();
    if (lane == 0) {
        int sa = lbase[a] + ra;
        int sb = lbase[b] + rb;
        tok[a * CAP + sa] = t;  gate[a * CAP + sa] = g0;
        tok[b * CAP + sb] = t;  gate[b * CAP + sb] = g1;
    }
}

// ---------------- prefix over 8 counts ----------------
__global__ void prefix_k(const int* __restrict__ counts, int* __restrict__ offs) {
    if (threadIdx.x == 0) {
        int s = 0;
        for (int e = 0; e < N_EXP; ++e) { offs[e] = s; s += counts[e]; }
    }
}

// ---------------- fc1: h = gelu(x_gathered @ w1^T + b1) ----------------
// Block 256 = 4 waves (2x2), each wave 64x64 via 4x4 MFMA 16x16x32 tiles.
__global__ __launch_bounds__(256) void fc1_k(const bf16* __restrict__ xb,
                                             const float* __restrict__ w1,
                                             const float* __restrict__ b1,
                                             const int* __restrict__ counts,
                                             const int* __restrict__ offs,
                                             const int* __restrict__ tok,
                                             bf16* __restrict__ h) {
    const int e   = blockIdx.z;
    const int cnt = counts[e];
    const int m0  = blockIdx.y * 128;
    if (m0 >= cnt) return;
    const int n0  = blockIdx.x * 128;
    const int off = offs[e];

    __shared__ __align__(16) bf16 As[128][32];
    __shared__ __align__(16) bf16 Bs[128][32];

    const int tid  = threadIdx.x;
    const int lane = tid & 63;
    const int wv   = tid >> 6;
    const int wm   = wv & 1;
    const int wn   = wv >> 1;

    // A staging (gathered rows of xb via global_load_lds, 2 chunks of 16 rows/wave)
    const int ar0  = wv * 16 + (lane >> 2);
    const int ar1  = 64 + wv * 16 + (lane >> 2);
    const int acol = (lane & 3) * 8;
    const int i0 = m0 + ar0; const int i1 = m0 + ar1;
    const int t0 = tok[e * CAP + (i0 < cnt ? i0 : cnt - 1)];
    const int t1 = tok[e * CAP + (i1 < cnt ? i1 : cnt - 1)];
    const bf16* ga0 = xb + (size_t)t0 * C_DIM + acol;
    const bf16* ga1 = xb + (size_t)t1 * C_DIM + acol;
    bf16* la0 = &As[wv * 16][0];
    bf16* la1 = &As[64 + wv * 16][0];

    // B staging (w1 fp32 -> bf16 cvt, 2 rows-of-64 iterations)
    const int brow0 = tid >> 2;
    const int brow1 = 64 + (tid >> 2);
    const int bcol  = (tid & 3) * 8;
    const float* gb0 = w1 + ((size_t)e * H_DIM + n0 + brow0) * C_DIM + bcol;
    const float* gb1 = w1 + ((size_t)e * H_DIM + n0 + brow1) * C_DIM + bcol;

    f32x4 acc[4][4];
#pragma unroll
    for (int mi = 0; mi < 4; ++mi)
#pragma unroll
        for (int ni = 0; ni < 4; ++ni)
#pragma unroll
            for (int r = 0; r < 4; ++r) acc[mi][ni][r] = 0.f;

    for (int kt = 0; kt < C_DIM / 32; ++kt) {
        const int k0 = kt * 32;
        async_ld16(ga0 + k0, la0);
        async_ld16(ga1 + k0, la1);
        {
            float4 u0 = *(const float4*)(gb0 + k0);
            float4 u1 = *(const float4*)(gb0 + k0 + 4);
            bf16x8 v;
            v[0]=(bf16)u0.x; v[1]=(bf16)u0.y; v[2]=(bf16)u0.z; v[3]=(bf16)u0.w;
            v[4]=(bf16)u1.x; v[5]=(bf16)u1.y; v[6]=(bf16)u1.z; v[7]=(bf16)u1.w;
            *(bf16x8*)&Bs[brow0][bcol] = v;
            float4 u2 = *(const float4*)(gb1 + k0);
            float4 u3 = *(const float4*)(gb1 + k0 + 4);
            bf16x8 w;
            w[0]=(bf16)u2.x; w[1]=(bf16)u2.y; w[2]=(bf16)u2.z; w[3]=(bf16)u2.w;
            w[4]=(bf16)u3.x; w[5]=(bf16)u3.y; w[6]=(bf16)u3.z; w[7]=(bf16)u3.w;
            *(bf16x8*)&Bs[brow1][bcol] = w;
        }
        __syncthreads();

        bf16x8 af[4];
#pragma unroll
        for (int mi = 0; mi < 4; ++mi)
            af[mi] = *(const bf16x8*)&As[wm * 64 + mi * 16 + (lane & 15)][(lane >> 4) * 8];
#pragma unroll
        for (int ni = 0; ni < 4; ++ni) {
            bf16x8 bfr = *(const bf16x8*)&Bs[wn * 64 + ni * 16 + (lane & 15)][(lane >> 4) * 8];
#pragma unroll
            for (int mi = 0; mi < 4; ++mi)
                acc[mi][ni] = __builtin_amdgcn_mfma_f32_16x16x32_bf16(af[mi], bfr, acc[mi][ni], 0, 0, 0);
        }
        __syncthreads();
    }

    const int lg = lane >> 4, ln = lane & 15;
#pragma unroll
    for (int mi = 0; mi < 4; ++mi) {
#pragma unroll
        for (int r = 0; r < 4; ++r) {
            const int m = wm * 64 + mi * 16 + lg * 4 + r;
            if (m0 + m < cnt) {
                const size_t hrow = (size_t)(off + m0 + m) * H_DIM;
#pragma unroll
                for (int ni = 0; ni < 4; ++ni) {
                    const int n = n0 + wn * 64 + ni * 16 + ln;
                    float v = acc[mi][ni][r] + b1[(size_t)e * H_DIM + n];
                    h[hrow + n] = (bf16)gelu_f(v);
                }
            }
        }
    }
}

// ---------------- fc2: out += gate * (h @ w2^T + b2) ----------------
__global__ __launch_bounds__(256) void fc2_k(const bf16* __restrict__ h,
                                             const float* __restrict__ w2,
                                             const float* __restrict__ b2,
                                             const int* __restrict__ counts,
                                             const int* __restrict__ offs,
                                             const int* __restrict__ tok,
                                             const float* __restrict__ gate,
                                             float* __restrict__ out) {
    const int e   = blockIdx.z;
    const int cnt = counts[e];
    const int m0  = blockIdx.y * 128;
    if (m0 >= cnt) return;
    const int n0  = blockIdx.x * 128;
    const int off = offs[e];

    __shared__ __align__(16) bf16 As[128][32];
    __shared__ __align__(16) bf16 Bs[128][32];

    const int tid  = threadIdx.x;
    const int lane = tid & 63;
    const int wv   = tid >> 6;
    const int wm   = wv & 1;
    const int wn   = wv >> 1;

    const int ar0  = wv * 16 + (lane >> 2);
    const int ar1  = 64 + wv * 16 + (lane >> 2);
    const int acol = (lane & 3) * 8;
    const int i0 = m0 + ar0; const int i1 = m0 + ar1;
    const size_t hr0 = (size_t)(off + (i0 < cnt ? i0 : cnt - 1)) * H_DIM;
    const size_t hr1 = (size_t)(off + (i1 < cnt ? i1 : cnt - 1)) * H_DIM;
    const bf16* ga0 = h + hr0 + acol;
    const bf16* ga1 = h + hr1 + acol;
    bf16* la0 = &As[wv * 16][0];
    bf16* la1 = &As[64 + wv * 16][0];

    const int brow0 = tid >> 2;
    const int brow1 = 64 + (tid >> 2);
    const int bcol  = (tid & 3) * 8;
    const float* gb0 = w2 + ((size_t)e * C_DIM + n0 + brow0) * H_DIM + bcol;
    const float* gb1 = w2 + ((size_t)e * C_DIM + n0 + brow1) * H_DIM + bcol;

    f32x4 acc[4][4];
#pragma unroll
    for (int mi = 0; mi < 4; ++mi)
#pragma unroll
        for (int ni = 0; ni < 4; ++ni)
#pragma unroll
            for (int r = 0; r < 4; ++r) acc[mi][ni][r] = 0.f;

    for (int kt = 0; kt < H_DIM / 32; ++kt) {
        const int k0 = kt * 32;
        async_ld16(ga0 + k0, la0);
        async_ld16(ga1 + k0, la1);
        {
            float4 u0 = *(const float4*)(gb0 + k0);
            float4 u1 = *(const float4*)(gb0 + k0 + 4);
            bf16x8 v;
            v[0]=(bf16)u0.x; v[1]=(bf16)u0.y; v[2]=(bf16)u0.z; v[3]=(bf16)u0.w;
            v[4]=(bf16)u1.x; v[5]=(bf16)u1.y; v[6]=(bf16)u1.z; v[7]=(bf16)u1.w;
            *(bf16x8*)&Bs[brow0][bcol] = v;
            float4 u2 = *(const float4*)(gb1 + k0);
            float4 u3 = *(const float4*)(gb1 + k0 + 4);
            bf16x8 w;
            w[0]=(bf16)u2.x; w[1]=(bf16)u2.y; w[2]=(bf16)u2.z; w[3]=(bf16)u2.w;
            w[4]=(bf16)u3.x; w[5]=(bf16)u3.y; w[6]=(bf16)u3.z; w[7]=(bf16)u3.w;
            *(bf16x8*)&Bs[brow1][bcol] = w;
        }
        __syncthreads();

        bf16x8 af[4];
#pragma unroll
        for (int mi = 0; mi < 4; ++mi)
            af[mi] = *(const bf16x8*)&As[wm * 64 + mi * 16 + (lane & 15)][(lane >> 4) * 8];
#pragma unroll
        for (int ni = 0; ni < 4; ++ni) {
            bf16x8 bfr = *(const bf16x8*)&Bs[wn * 64 + ni * 16 + (lane & 15)][(lane >> 4) * 8];
#pragma unroll
            for (int mi = 0; mi < 4; ++mi)
                acc[mi][ni] = __builtin_amdgcn_mfma_f32_16x16x32_bf16(af[mi], bfr, acc[mi][ni], 0, 0, 0);
        }
        __syncthreads();
    }

    const int lg = lane >> 4, ln = lane & 15;
#pragma unroll
    for (int mi = 0; mi < 4; ++mi) {
#pragma unroll
        for (int r = 0; r < 4; ++r) {
            const int m = wm * 64 + mi * 16 + lg * 4 + r;
            if (m0 + m < cnt) {
                const int   tk = tok[e * CAP + m0 + m];
                const float g  = gate[e * CAP + m0 + m];
#pragma unroll
                for (int ni = 0; ni < 4; ++ni) {
                    const int n = n0 + wn * 64 + ni * 16 + ln;
                    float v = (acc[mi][ni][r] + b2[(size_t)e * C_DIM + n]) * g;
                    atomicAdd(&out[(size_t)tk * C_DIM + n], v);
                }
            }
        }
    }
}

extern "C" void kernel_launch(void* const* d_in, const int* in_sizes, int n_in,
                              void* d_out, int out_size, void* d_ws, size_t ws_size,
                              hipStream_t stream) {
    const float* x  = (const float*)d_in[0];
    const float* rw = (const float*)d_in[1];
    const float* w1 = (const float*)d_in[2];
    const float* b1 = (const float*)d_in[3];
    const float* w2 = (const float*)d_in[4];
    const float* b2 = (const float*)d_in[5];
    float* out = (float*)d_out;

    // ws layout (needs ~145 MiB)
    char* ws = (char*)d_ws;
    size_t o = 0;
    bf16* xb     = (bf16*)(ws + o);  o += (size_t)N_TOK * C_DIM * sizeof(bf16);   // 16 MiB
    int*  tok    = (int*)(ws + o);   o += (size_t)N_EXP * CAP * sizeof(int);      // 256 KiB
    float* gate  = (float*)(ws + o); o += (size_t)N_EXP * CAP * sizeof(float);    // 256 KiB
    int*  counts = (int*)(ws + o);   o += 128;
    int*  offs   = (int*)(ws + o);   o += 128;
    bf16* h      = (bf16*)(ws + o);  o += (size_t)(2 * N_TOK) * H_DIM * sizeof(bf16); // 128 MiB

    hipMemsetAsync(d_out, 0, (size_t)N_TOK * C_DIM * sizeof(float), stream);
    hipMemsetAsync(counts, 0, 128, stream);

    cvt_x_k<<<dim3((N_TOK * C_DIM / 8 + 255) / 256), dim3(256), 0, stream>>>(x, xb, N_TOK * C_DIM / 8);
    router_k<<<dim3(N_TOK / 16), dim3(1024), 0, stream>>>(x, rw, counts, tok, gate);
    prefix_k<<<dim3(1), dim3(64), 0, stream>>>(counts, offs);
    fc1_k<<<dim3(H_DIM / 128, N_TOK / 128, N_EXP), dim3(256), 0, stream>>>(xb, w1, b1, counts, offs, tok, h);
    fc2_k<<<dim3(C_DIM / 128, N_TOK / 128, N_EXP), dim3(256), 0, stream>>>(h, w2, b2, counts, offs, tok, gate, out);
}

// Round 2
// 908.520 us; speedup vs baseline: 1.0762x; 1.0762x over previous
//
#include <hip/hip_runtime.h>
#include <hip/hip_bf16.h>
#include <math.h>

// MoE FFN: N=8192 tokens, C=1024, H=4096, E=8, TOP_K=2.
// Round 2: pre-convert weights to bf16; global_load_lds for A AND B;
// XOR-swizzled LDS layout (conflict-free ds_read_b128).
//   router (fp32) -> per-expert compacted token lists
//   fc1: h = gelu(x_gathered @ w1^T)   [bf16 MFMA, fp32 acc]
//   fc2: out += gate * (h @ w2^T)      [atomicAdd fp32 scatter]

#define N_TOK   8192
#define C_DIM   1024
#define H_DIM   4096
#define N_EXP   8
#define CAP     8192   // per-expert worst-case capacity

typedef __bf16 bf16;
typedef bf16  bf16x8 __attribute__((ext_vector_type(8)));
typedef float f32x4  __attribute__((ext_vector_type(4)));

__device__ __forceinline__ void async_ld16(const void* g, void* l) {
    __builtin_amdgcn_global_load_lds(
        (const __attribute__((address_space(1))) void*)g,
        (__attribute__((address_space(3))) void*)l,
        16, 0, 0);
}

__device__ __forceinline__ float gelu_f(float v) {
    float u = v + 0.044715f * v * v * v;
    return 0.5f * v * (1.0f + tanhf(0.7978845608028654f * u));
}

// ---------------- fp32 -> bf16 (x and weights) ----------------
__global__ void cvt_k(const float* __restrict__ src, bf16* __restrict__ dst, int n8) {
    int i = blockIdx.x * blockDim.x + threadIdx.x;
    if (i >= n8) return;
    const float4* p = (const float4*)src + (size_t)i * 2;
    float4 a = p[0], b = p[1];
    bf16x8 v;
    v[0] = (bf16)a.x; v[1] = (bf16)a.y; v[2] = (bf16)a.z; v[3] = (bf16)a.w;
    v[4] = (bf16)b.x; v[5] = (bf16)b.y; v[6] = (bf16)b.z; v[7] = (bf16)b.w;
    *((bf16x8*)dst + i) = v;
}

// ---------------- router: logits -> softmax -> top2 -> compacted lists ----------------
__global__ __launch_bounds__(1024) void router_k(const float* __restrict__ x,
                                                 const float* __restrict__ rw,
                                                 int* __restrict__ counts,
                                                 int* __restrict__ tok,
                                                 float* __restrict__ gate) {
    __shared__ int lcnt[N_EXP];
    __shared__ int lbase[N_EXP];
    const int tid  = threadIdx.x;
    const int lane = tid & 63;
    const int wv   = tid >> 6;          // 16 waves -> 16 tokens per block
    if (tid < N_EXP) lcnt[tid] = 0;
    __syncthreads();

    const int t = blockIdx.x * 16 + wv;

    float dot[N_EXP];
#pragma unroll
    for (int e = 0; e < N_EXP; ++e) dot[e] = 0.f;
    const float4* xr = (const float4*)(x + (size_t)t * C_DIM);
#pragma unroll
    for (int j = 0; j < 4; ++j) {
        float4 xv = xr[j * 64 + lane];
#pragma unroll
        for (int e = 0; e < N_EXP; ++e) {
            float4 w4 = ((const float4*)(rw + (size_t)e * C_DIM))[j * 64 + lane];
            dot[e] += xv.x * w4.x + xv.y * w4.y + xv.z * w4.z + xv.w * w4.w;
        }
    }
#pragma unroll
    for (int e = 0; e < N_EXP; ++e) {
#pragma unroll
        for (int o = 32; o > 0; o >>= 1) dot[e] += __shfl_xor(dot[e], o, 64);
    }

    int a = 0, b = 0, ra = 0, rb = 0;
    float g0 = 0.f, g1 = 0.f;
    if (lane == 0) {
        float m = dot[0];
#pragma unroll
        for (int e = 1; e < N_EXP; ++e) m = fmaxf(m, dot[e]);
        float p[N_EXP]; float s = 0.f;
#pragma unroll
        for (int e = 0; e < N_EXP; ++e) { p[e] = expf(dot[e] - m); s += p[e]; }
        a = 0;
#pragma unroll
        for (int e = 1; e < N_EXP; ++e) if (p[e] > p[a]) a = e;
        b = -1;
#pragma unroll
        for (int e = 0; e < N_EXP; ++e) if (e != a && (b < 0 || p[e] > p[b])) b = e;
        float pa = p[a] / s, pb = p[b] / s;
        float d = pa + pb + 1e-8f;
        g0 = pa / d; g1 = pb / d;
        ra = atomicAdd(&lcnt[a], 1);
        rb = atomicAdd(&lcnt[b], 1);
    }
    __syncthreads();
    if (tid < N_EXP) lbase[tid] = atomicAdd(&counts[tid], lcnt[tid]);
    __syncthreads();
    if (lane == 0) {
        int sa = lbase[a] + ra;
        int sb = lbase[b] + rb;
        tok[a * CAP + sa] = t;  gate[a * CAP + sa] = g0;
        tok[b * CAP + sb] = t;  gate[b * CAP + sb] = g1;
    }
}

// ---------------- prefix over 8 counts ----------------
__global__ void prefix_k(const int* __restrict__ counts, int* __restrict__ offs) {
    if (threadIdx.x == 0) {
        int s = 0;
        for (int e = 0; e < N_EXP; ++e) { offs[e] = s; s += counts[e]; }
    }
}

// XOR swizzle: LDS chunk (row, c) holds global 8-elem group (row, c ^ s(row)),
// s(row) = (row>>1)&3.  Staging lane l (within a 16-row block): row = l>>2,
// c = l&3  => global col group = (l&3) ^ ((l>>3)&3).
// Fragment read (m-row r = lane&15, k-group g = lane>>4): chunk c = g ^ ((r>>1)&3).
// => each group of 8 consecutive lanes of a ds_read_b128 covers all 32 banks once.

// ---------------- fc1: h = gelu(x_gathered @ w1^T + b1) ----------------
__global__ __launch_bounds__(256) void fc1_k(const bf16* __restrict__ xb,
                                             const bf16* __restrict__ w1b,
                                             const float* __restrict__ b1,
                                             const int* __restrict__ counts,
                                             const int* __restrict__ offs,
                                             const int* __restrict__ tok,
                                             bf16* __restrict__ h) {
    const int e   = blockIdx.z;
    const int cnt = counts[e];
    const int m0  = blockIdx.y * 128;
    if (m0 >= cnt) return;
    const int n0  = blockIdx.x * 128;
    const int off = offs[e];

    __shared__ __align__(16) bf16 As[128][32];
    __shared__ __align__(16) bf16 Bs[128][32];

    const int tid  = threadIdx.x;
    const int lane = tid & 63;
    const int wv   = tid >> 6;
    const int wm   = wv & 1;
    const int wn   = wv >> 1;

    // swizzled source column (elements) for staging
    const int scol = (((lane & 3) ^ ((lane >> 3) & 3))) * 8;

    // A staging: wave wv stages rows [wv*16, wv*16+16) and [64+wv*16, ...)
    const int ar0 = wv * 16 + (lane >> 2);
    const int ar1 = 64 + wv * 16 + (lane >> 2);
    const int i0 = m0 + ar0, i1 = m0 + ar1;
    const int t0 = tok[e * CAP + (i0 < cnt ? i0 : cnt - 1)];
    const int t1 = tok[e * CAP + (i1 < cnt ? i1 : cnt - 1)];
    const bf16* ga0 = xb + (size_t)t0 * C_DIM + scol;
    const bf16* ga1 = xb + (size_t)t1 * C_DIM + scol;
    bf16* la0 = &As[wv * 16][0];
    bf16* la1 = &As[64 + wv * 16][0];

    // B staging: same shape, rows of w1b
    const bf16* gb0 = w1b + ((size_t)e * H_DIM + n0 + ar0) * C_DIM + scol;
    const bf16* gb1 = w1b + ((size_t)e * H_DIM + n0 + ar1) * C_DIM + scol;
    bf16* lb0 = &Bs[wv * 16][0];
    bf16* lb1 = &Bs[64 + wv * 16][0];

    f32x4 acc[4][4];
#pragma unroll
    for (int mi = 0; mi < 4; ++mi)
#pragma unroll
        for (int ni = 0; ni < 4; ++ni)
#pragma unroll
            for (int r = 0; r < 4; ++r) acc[mi][ni][r] = 0.f;

    const int r_   = lane & 15;
    const int g_   = lane >> 4;
    const int rcol = (g_ ^ ((r_ >> 1) & 3)) * 8;   // swizzled read column

    for (int kt = 0; kt < C_DIM / 32; ++kt) {
        const int k0 = kt * 32;
        async_ld16(ga0 + k0, la0);
        async_ld16(ga1 + k0, la1);
        async_ld16(gb0 + k0, lb0);
        async_ld16(gb1 + k0, lb1);
        __syncthreads();

        bf16x8 af[4];
#pragma unroll
        for (int mi = 0; mi < 4; ++mi)
            af[mi] = *(const bf16x8*)&As[wm * 64 + mi * 16 + r_][rcol];
#pragma unroll
        for (int ni = 0; ni < 4; ++ni) {
            bf16x8 bfr = *(const bf16x8*)&Bs[wn * 64 + ni * 16 + r_][rcol];
#pragma unroll
            for (int mi = 0; mi < 4; ++mi)
                acc[mi][ni] = __builtin_amdgcn_mfma_f32_16x16x32_bf16(af[mi], bfr, acc[mi][ni], 0, 0, 0);
        }
        __syncthreads();
    }

    const int lg = lane >> 4, ln = lane & 15;
#pragma unroll
    for (int mi = 0; mi < 4; ++mi) {
#pragma unroll
        for (int r = 0; r < 4; ++r) {
            const int m = wm * 64 + mi * 16 + lg * 4 + r;
            if (m0 + m < cnt) {
                const size_t hrow = (size_t)(off + m0 + m) * H_DIM;
#pragma unroll
                for (int ni = 0; ni < 4; ++ni) {
                    const int n = n0 + wn * 64 + ni * 16 + ln;
                    float v = acc[mi][ni][r] + b1[(size_t)e * H_DIM + n];
                    h[hrow + n] = (bf16)gelu_f(v);
                }
            }
        }
    }
}

// ---------------- fc2: out += gate * (h @ w2^T + b2) ----------------
__global__ __launch_bounds__(256) void fc2_k(const bf16* __restrict__ h,
                                             const bf16* __restrict__ w2b,
                                             const float* __restrict__ b2,
                                             const int* __restrict__ counts,
                                             const int* __restrict__ offs,
                                             const int* __restrict__ tok,
                                             const float* __restrict__ gate,
                                             float* __restrict__ out) {
    const int e   = blockIdx.z;
    const int cnt = counts[e];
    const int m0  = blockIdx.y * 128;
    if (m0 >= cnt) return;
    const int n0  = blockIdx.x * 128;
    const int off = offs[e];

    __shared__ __align__(16) bf16 As[128][32];
    __shared__ __align__(16) bf16 Bs[128][32];

    const int tid  = threadIdx.x;
    const int lane = tid & 63;
    const int wv   = tid >> 6;
    const int wm   = wv & 1;
    const int wn   = wv >> 1;

    const int scol = (((lane & 3) ^ ((lane >> 3) & 3))) * 8;

    const int ar0 = wv * 16 + (lane >> 2);
    const int ar1 = 64 + wv * 16 + (lane >> 2);
    const int i0 = m0 + ar0, i1 = m0 + ar1;
    const size_t hr0 = (size_t)(off + (i0 < cnt ? i0 : cnt - 1)) * H_DIM;
    const size_t hr1 = (size_t)(off + (i1 < cnt ? i1 : cnt - 1)) * H_DIM;
    const bf16* ga0 = h + hr0 + scol;
    const bf16* ga1 = h + hr1 + scol;
    bf16* la0 = &As[wv * 16][0];
    bf16* la1 = &As[64 + wv * 16][0];

    const bf16* gb0 = w2b + ((size_t)e * C_DIM + n0 + ar0) * H_DIM + scol;
    const bf16* gb1 = w2b + ((size_t)e * C_DIM + n0 + ar1) * H_DIM + scol;
    bf16* lb0 = &Bs[wv * 16][0];
    bf16* lb1 = &Bs[64 + wv * 16][0];

    f32x4 acc[4][4];
#pragma unroll
    for (int mi = 0; mi < 4; ++mi)
#pragma unroll
        for (int ni = 0; ni < 4; ++ni)
#pragma unroll
            for (int r = 0; r < 4; ++r) acc[mi][ni][r] = 0.f;

    const int r_   = lane & 15;
    const int g_   = lane >> 4;
    const int rcol = (g_ ^ ((r_ >> 1) & 3)) * 8;

    for (int kt = 0; kt < H_DIM / 32; ++kt) {
        const int k0 = kt * 32;
        async_ld16(ga0 + k0, la0);
        async_ld16(ga1 + k0, la1);
        async_ld16(gb0 + k0, lb0);
        async_ld16(gb1 + k0, lb1);
        __syncthreads();

        bf16x8 af[4];
#pragma unroll
        for (int mi = 0; mi < 4; ++mi)
            af[mi] = *(const bf16x8*)&As[wm * 64 + mi * 16 + r_][rcol];
#pragma unroll
        for (int ni = 0; ni < 4; ++ni) {
            bf16x8 bfr = *(const bf16x8*)&Bs[wn * 64 + ni * 16 + r_][rcol];
#pragma unroll
            for (int mi = 0; mi < 4; ++mi)
                acc[mi][ni] = __builtin_amdgcn_mfma_f32_16x16x32_bf16(af[mi], bfr, acc[mi][ni], 0, 0, 0);
        }
        __syncthreads();
    }

    const int lg = lane >> 4, ln = lane & 15;
#pragma unroll
    for (int mi = 0; mi < 4; ++mi) {
#pragma unroll
        for (int r = 0; r < 4; ++r) {
            const int m = wm * 64 + mi * 16 + lg * 4 + r;
            if (m0 + m < cnt) {
                const int   tk = tok[e * CAP + m0 + m];
                const float g  = gate[e * CAP + m0 + m];
#pragma unroll
                for (int ni = 0; ni < 4; ++ni) {
                    const int n = n0 + wn * 64 + ni * 16 + ln;
                    float v = (acc[mi][ni][r] + b2[(size_t)e * C_DIM + n]) * g;
                    atomicAdd(&out[(size_t)tk * C_DIM + n], v);
                }
            }
        }
    }
}

extern "C" void kernel_launch(void* const* d_in, const int* in_sizes, int n_in,
                              void* d_out, int out_size, void* d_ws, size_t ws_size,
                              hipStream_t stream) {
    const float* x  = (const float*)d_in[0];
    const float* rw = (const float*)d_in[1];
    const float* w1 = (const float*)d_in[2];
    const float* b1 = (const float*)d_in[3];
    const float* w2 = (const float*)d_in[4];
    const float* b2 = (const float*)d_in[5];
    float* out = (float*)d_out;

    // ws layout (~280 MiB)
    char* ws = (char*)d_ws;
    size_t o = 0;
    bf16* xb     = (bf16*)(ws + o);  o += (size_t)N_TOK * C_DIM * sizeof(bf16);        // 16 MiB
    bf16* w1b    = (bf16*)(ws + o);  o += (size_t)N_EXP * H_DIM * C_DIM * sizeof(bf16); // 64 MiB
    bf16* w2b    = (bf16*)(ws + o);  o += (size_t)N_EXP * C_DIM * H_DIM * sizeof(bf16); // 64 MiB
    int*  tok    = (int*)(ws + o);   o += (size_t)N_EXP * CAP * sizeof(int);           // 256 KiB
    float* gate  = (float*)(ws + o); o += (size_t)N_EXP * CAP * sizeof(float);         // 256 KiB
    int*  counts = (int*)(ws + o);   o += 128;
    int*  offs   = (int*)(ws + o);   o += 128;
    bf16* h      = (bf16*)(ws + o);  o += (size_t)(2 * N_TOK) * H_DIM * sizeof(bf16);  // 128 MiB

    hipMemsetAsync(d_out, 0, (size_t)N_TOK * C_DIM * sizeof(float), stream);
    hipMemsetAsync(counts, 0, 128, stream);

    const int NW = N_EXP * H_DIM * C_DIM / 8;  // 4.19M vec8 groups per weight tensor
    cvt_k<<<dim3((N_TOK * C_DIM / 8 + 255) / 256), 256, 0, stream>>>(x, xb, N_TOK * C_DIM / 8);
    cvt_k<<<dim3((NW + 255) / 256), 256, 0, stream>>>(w1, w1b, NW);
    cvt_k<<<dim3((NW + 255) / 256), 256, 0, stream>>>(w2, w2b, NW);
    router_k<<<dim3(N_TOK / 16), dim3(1024), 0, stream>>>(x, rw, counts, tok, gate);
    prefix_k<<<dim3(1), dim3(64), 0, stream>>>(counts, offs);
    fc1_k<<<dim3(H_DIM / 128, N_TOK / 128, N_EXP), dim3(256), 0, stream>>>(xb, w1b, b1, counts, offs, tok, h);
    fc2_k<<<dim3(C_DIM / 128, N_TOK / 128, N_EXP), dim3(256), 0, stream>>>(h, w2b, b2, counts, offs, tok, gate, out);
}